// Round 1
// 353.909 us; speedup vs baseline: 1.2031x; 1.2031x over previous
//
#include <hip/hip_runtime.h>
#include <hip/hip_bf16.h>

using bf16 = __hip_bfloat16;

typedef __attribute__((ext_vector_type(8))) short bf16x8;
typedef __attribute__((ext_vector_type(4))) float f32x4;

// async global->LDS, 16 B per lane, wave-uniform LDS base (+lane*16 by HW).
__device__ __forceinline__ void async16(const void* g, void* l) {
  __builtin_amdgcn_global_load_lds(
      (const __attribute__((address_space(1))) unsigned int*)g,
      (__attribute__((address_space(3))) unsigned int*)l, 16, 0, 0);
}

__device__ __forceinline__ void store_o(float* C, size_t i, float v) { C[i] = v; }
__device__ __forceinline__ void store_o(bf16* C, size_t i, float v) {
  C[i] = __float2bfloat16(v);
}

// ---------------------------------------------------------------------------
// K1: backbone conv (3->256, 3x3, stride16, pad1) fused with 2x2 avgpool.
// Output f NHWC fp32 (8,32,32,256). One block per (b,y,x), thread=cout.
// ---------------------------------------------------------------------------
__global__ __launch_bounds__(256) void k_backbone(const float* __restrict__ img,
    const float* __restrict__ w, const float* __restrict__ bias,
    float* __restrict__ f) {
  int blk = blockIdx.x;
  int x = blk & 31, y = (blk >> 5) & 31, b = blk >> 10;
  __shared__ float patch[4 * 27];   // [sub][cin*9+ky*3+kx]
  int t = threadIdx.x;
  if (t < 108) {
    int kx = t % 3, ky = (t / 3) % 3, cin = (t / 9) % 3, sub = t / 27;
    int sy = sub >> 1, sx = sub & 1;
    int iy = (2 * y + sy) * 16 - 1 + ky;   // max 1009 < 1024
    int ix = (2 * x + sx) * 16 - 1 + kx;
    float v = 0.f;
    if (iy >= 0 && ix >= 0)
      v = img[((size_t)(b * 3 + cin) * 1024 + iy) * 1024 + ix];
    patch[t] = v;
  }
  __syncthreads();
  int c = t;
  float wr[27];
#pragma unroll
  for (int k = 0; k < 27; ++k) wr[k] = w[c * 27 + k];
  float acc = 0.f;
#pragma unroll
  for (int sub = 0; sub < 4; ++sub)
#pragma unroll
    for (int k = 0; k < 27; ++k)
      acc += patch[sub * 27 + k] * wr[k];
  f[(size_t)blk * 256 + c] = acc * 0.25f + bias[c];
}

// ---------------------------------------------------------------------------
// K2a: RPN conv partials. grid (pos=32, kc=16), thread = cout.
// Each block handles 16 input channels for one (b,x) position (y=0 row only;
// only the first 100 proposals per batch are ever consumed).
// part[(kc*32+pos)*256 + cout] = partial sum over this block's 16 cins.
// Per-thread weight window is 576 contiguous bytes -> compiler emits merged
// dwordx4/x2 loads, ~96 independent loads in flight (MLP hides L2 latency).
// ---------------------------------------------------------------------------
__global__ __launch_bounds__(256) void k_rpn(const float* __restrict__ f,
    const float* __restrict__ rpn_w, float* __restrict__ part) {
  int p = blockIdx.x;        // 0..31 : b*4 + x
  int kc = blockIdx.y;       // 0..15 : 16-cin chunk
  int x = p & 3, b = p >> 2;
  __shared__ float fpl[6][16];   // [row*3+col][cin2]
  int tid = threadIdx.x;
  if (tid < 96) {
    int cin2 = tid & 15;
    int rc = tid >> 4;       // 0..5 = row*3+col
    int row = rc / 3, col = rc % 3;
    int xc = x - 1 + col;    // <= 5, always < 32
    float v = 0.f;
    if (xc >= 0)
      v = f[((size_t)(b * 32 + row) * 32 + xc) * 256 + kc * 16 + cin2];
    fpl[rc][cin2] = v;
  }
  __syncthreads();
  int c = tid;
  const float* wbase = rpn_w + (size_t)c * 2304 + kc * 144;
  float acc = 0.f;
#pragma unroll
  for (int cin2 = 0; cin2 < 16; ++cin2) {
    const float* wp = wbase + cin2 * 9;
    // taps 3..8 = (row,col) in row-major over rows {0,1} (row -1 is padding)
    acc += fpl[0][cin2] * wp[3] + fpl[1][cin2] * wp[4]
         + fpl[2][cin2] * wp[5] + fpl[3][cin2] * wp[6]
         + fpl[4][cin2] * wp[7] + fpl[5][cin2] * wp[8];
  }
  part[((size_t)kc * 32 + p) * 256 + c] = acc;
}

// ---------------------------------------------------------------------------
// K2b: reduce partials + ReLU, delta conv (2 threads per output), decode.
// 32 blocks (one per pos), 512 threads.
// ---------------------------------------------------------------------------
__global__ __launch_bounds__(512) void k_delta(const float* __restrict__ part,
    const float* __restrict__ rpn_b,
    const float* __restrict__ dw, const float* __restrict__ db,
    float* __restrict__ boxes) {
  int p = blockIdx.x;        // 0..31
  int x = p & 3, b = p >> 2;
  __shared__ float tbuf[256];
  __shared__ float dvals[135];
  int tid = threadIdx.x;
  if (tid < 256) {
    float s = rpn_b[tid];
#pragma unroll
    for (int kc = 0; kc < 16; ++kc)
      s += part[((size_t)kc * 32 + p) * 256 + tid];
    tbuf[tid] = fmaxf(s, 0.f);
  }
  __syncthreads();
  if (tid < 270) {
    int o = tid >> 1, half = tid & 1;
    const float* wp = dw + (size_t)o * 256 + half * 128;
    const float* tp = tbuf + half * 128;
    float s = 0.f;
#pragma unroll 8
    for (int k = 0; k < 128; ++k) s += tp[k] * wp[k];
    s += __shfl_xor(s, 1, 64);   // pair (2o, 2o+1) always within one wave
    if (half == 0) dvals[o] = s + db[o];
  }
  __syncthreads();
  if (tid < 27) {
    int i = x * 27 + tid;
    if (i < 100) {
      int a = tid;
      int si = a / 9, ri = (a / 3) % 3, ai = a % 3;
      float scale = 32.f * (float)(1 << si);
      float sr = (ri == 0) ? 0.70710678118654752f : (ri == 1 ? 1.0f : 1.41421356237309505f);
      float aw = scale * sr, ah = scale / sr;
      float aang = 45.f * (float)ai;
      float acx = 32.f * (float)x, acy = 0.f;
      float* bx = boxes + (size_t)(b * 100 + i) * 5;
      bx[0] = dvals[a * 5 + 0] * aw + acx;
      bx[1] = dvals[a * 5 + 1] * ah + acy;
      bx[2] = expf(dvals[a * 5 + 2]) * aw;
      bx[3] = expf(dvals[a * 5 + 3]) * ah;
      bx[4] = aang + dvals[a * 5 + 4];
    }
  }
}

// ---------------------------------------------------------------------------
// K3: rotated ROI align. 800 blocks, thread=channel; writes pooled as bf16
// in (n, c*49+bin) order — the A operand of the FC1 MFMA GEMM.
// ---------------------------------------------------------------------------
__global__ __launch_bounds__(256) void k_roialign(const float* __restrict__ f,
    const float* __restrict__ boxes, bf16* __restrict__ pooled) {
  int n = blockIdx.x;
  int b = n / 100;
  __shared__ int six[49], siy[49];
  __shared__ float swx[49], swy[49];
  __shared__ float pool_s[12544];
  int tid = threadIdx.x;
  if (tid < 49) {
    float cx = boxes[n * 5 + 0], cy = boxes[n * 5 + 1];
    float w = boxes[n * 5 + 2], h = boxes[n * 5 + 3], ang = boxes[n * 5 + 4];
    float ar = -ang * 0.017453292519943295f;
    float cc = cosf(ar), ss = sinf(ar);
    float t00 = w * (1.f / 32.f) * cc, t01 = -h * (1.f / 32.f) * ss;
    float t02 = cx * (2.f / 32.f) - 1.f;
    float t10 = w * (1.f / 32.f) * ss, t11 = h * (1.f / 32.f) * cc;
    float t12 = cy * (2.f / 32.f) - 1.f;
    int py = tid / 7, px = tid - py * 7;
    float lx = (2.f * px + 1.f) * (1.f / 7.f) - 1.f;
    float ly = (2.f * py + 1.f) * (1.f / 7.f) - 1.f;
    float gx = t00 * lx + t01 * ly + t02;
    float gy = t10 * lx + t11 * ly + t12;
    float ix = ((gx + 1.f) * 32.f - 1.f) * 0.5f;
    float iy = ((gy + 1.f) * 32.f - 1.f) * 0.5f;
    float x0 = floorf(ix), y0 = floorf(iy);
    six[tid] = (int)x0; siy[tid] = (int)y0;
    swx[tid] = ix - x0; swy[tid] = iy - y0;
  }
  __syncthreads();
  const float* fb = f + (size_t)b * 262144;
  int c = tid;
  for (int bin = 0; bin < 49; ++bin) {
    int x0 = six[bin], y0 = siy[bin];
    float wx = swx[bin], wy = swy[bin];
    float acc = 0.f;
    if (x0 >= 0 && x0 < 32 && y0 >= 0 && y0 < 32)
      acc += fb[(y0 * 32 + x0) * 256 + c] * ((1.f - wx) * (1.f - wy));
    if (x0 + 1 >= 0 && x0 + 1 < 32 && y0 >= 0 && y0 < 32)
      acc += fb[(y0 * 32 + x0 + 1) * 256 + c] * (wx * (1.f - wy));
    if (x0 >= 0 && x0 < 32 && y0 + 1 >= 0 && y0 + 1 < 32)
      acc += fb[((y0 + 1) * 32 + x0) * 256 + c] * ((1.f - wx) * wy);
    if (x0 + 1 >= 0 && x0 + 1 < 32 && y0 + 1 >= 0 && y0 + 1 < 32)
      acc += fb[((y0 + 1) * 32 + x0 + 1) * 256 + c] * (wx * wy);
    pool_s[c * 49 + bin] = acc;
  }
  __syncthreads();
  bf16* po = pooled + (size_t)n * 12544;
  for (int k = tid; k < 12544; k += 256) po[k] = __float2bfloat16(pool_s[k]);
}

// ---------------------------------------------------------------------------
// K4: split-K MFMA GEMM partial: P[z] = A[:, kbeg:kend] * B[:, kbeg:kend]^T.
// A: MxK bf16 (async LDS, XOR-seg swizzle vs 128B-row bank aliasing),
// B: NxK fp32 (inline cvt, rows padded to 72 shorts), fp32 partials.
// 64x64 tile, BK=64, 4 waves. grid (N/64, ceil(M/64), KS).
// ---------------------------------------------------------------------------
__global__ __launch_bounds__(256) void k_gemm_sk(
    const unsigned short* __restrict__ A, const float* __restrict__ B,
    float* __restrict__ P, int M, int N, int K, int KC) {
  __shared__ unsigned short As[64 * 64];   // 8 KB, XOR-swizzled segs
  __shared__ unsigned short Bs[64 * 72];   // 9 KB, padded rows
  int t = threadIdx.x;
  int wv = t >> 6, ln = t & 63;
  int quad = ln >> 4, l15 = ln & 15;
  int n0 = blockIdx.x * 64, m0 = blockIdx.y * 64;
  int kbeg = blockIdx.z * KC;
  int kend = kbeg + KC; if (kend > K) kend = K;

  // A staging: lane covers (row arow(+32), global seg sg); LDS slot fixed at
  // wave_base + lane*16 == row*128 + (sg ^ (row&7))*16  (XOR swizzle).
  int arow = wv * 8 + (ln >> 3);
  int sg = (ln & 7) ^ (arow & 7);
  int r0 = m0 + arow;      if (r0 > M - 1) r0 = M - 1;
  int r1 = m0 + arow + 32; if (r1 > M - 1) r1 = M - 1;
  const unsigned short* Ap0 = A + (size_t)r0 * K + sg * 8;
  const unsigned short* Ap1 = A + (size_t)r1 * K + sg * 8;
  unsigned short* ldsA0 = &As[wv * 512];
  unsigned short* ldsA1 = &As[2048 + wv * 512];

  // B staging: thread covers row t>>2, 16 floats at (t&3)*16.
  int brow = t >> 2, bq = t & 3;
  const float* Bp = B + (size_t)(n0 + brow) * K + bq * 16;
  unsigned short* bdst = &Bs[brow * 72 + bq * 16];

  f32x4 acc[4];
#pragma unroll
  for (int j = 0; j < 4; ++j) acc[j] = (f32x4){0.f, 0.f, 0.f, 0.f};

  int mrow = wv * 16 + l15;   // this lane's A fragment row

  for (int k0 = kbeg; k0 < kend; k0 += 64) {
    float4 bv0 = *(const float4*)(Bp + k0);
    float4 bv1 = *(const float4*)(Bp + k0 + 4);
    float4 bv2 = *(const float4*)(Bp + k0 + 8);
    float4 bv3 = *(const float4*)(Bp + k0 + 12);
    __syncthreads();   // previous iteration's compute done
    async16(Ap0 + k0, ldsA0);
    async16(Ap1 + k0, ldsA1);
    unsigned short bb[16];
    bb[0]  = __bfloat16_as_ushort(__float2bfloat16(bv0.x));
    bb[1]  = __bfloat16_as_ushort(__float2bfloat16(bv0.y));
    bb[2]  = __bfloat16_as_ushort(__float2bfloat16(bv0.z));
    bb[3]  = __bfloat16_as_ushort(__float2bfloat16(bv0.w));
    bb[4]  = __bfloat16_as_ushort(__float2bfloat16(bv1.x));
    bb[5]  = __bfloat16_as_ushort(__float2bfloat16(bv1.y));
    bb[6]  = __bfloat16_as_ushort(__float2bfloat16(bv1.z));
    bb[7]  = __bfloat16_as_ushort(__float2bfloat16(bv1.w));
    bb[8]  = __bfloat16_as_ushort(__float2bfloat16(bv2.x));
    bb[9]  = __bfloat16_as_ushort(__float2bfloat16(bv2.y));
    bb[10] = __bfloat16_as_ushort(__float2bfloat16(bv2.z));
    bb[11] = __bfloat16_as_ushort(__float2bfloat16(bv2.w));
    bb[12] = __bfloat16_as_ushort(__float2bfloat16(bv3.x));
    bb[13] = __bfloat16_as_ushort(__float2bfloat16(bv3.y));
    bb[14] = __bfloat16_as_ushort(__float2bfloat16(bv3.z));
    bb[15] = __bfloat16_as_ushort(__float2bfloat16(bv3.w));
#pragma unroll
    for (int u = 0; u < 2; ++u)
      *(bf16x8*)(bdst + u * 8) = *(const bf16x8*)(bb + u * 8);
    __syncthreads();   // drains vmcnt (async A) + lgkm (B writes)
#pragma unroll
    for (int ks = 0; ks < 2; ++ks) {
      bf16x8 a = *(const bf16x8*)&As[mrow * 64 + (((ks * 4 + quad) ^ (mrow & 7)) * 8)];
#pragma unroll
      for (int j = 0; j < 4; ++j) {
        bf16x8 b = *(const bf16x8*)&Bs[(j * 16 + l15) * 72 + ks * 32 + quad * 8];
        acc[j] = __builtin_amdgcn_mfma_f32_16x16x32_bf16(a, b, acc[j], 0, 0, 0);
      }
    }
  }
  // store fp32 partials; D layout m = quad*4+r, n = l15 (within 16x16).
  float* Pz = P + (size_t)blockIdx.z * M * N;
#pragma unroll
  for (int j = 0; j < 4; ++j) {
    int n = n0 + j * 16 + l15;
#pragma unroll
    for (int r = 0; r < 4; ++r) {
      int m = m0 + wv * 16 + quad * 4 + r;
      if (m < M) Pz[(size_t)m * N + n] = acc[j][r];
    }
  }
}

// ---------------------------------------------------------------------------
// K5: split-K reduce: C = relu(sum_z P[z] + bias). float4-vectorized.
// ---------------------------------------------------------------------------
template <typename OutT, int KS>
__global__ __launch_bounds__(256) void k_reduce(const float* __restrict__ P,
    const float* __restrict__ bias, OutT* __restrict__ C, int MN, int N) {
  int i = blockIdx.x * 256 + threadIdx.x;   // float4 index
  if (i * 4 >= MN) return;
  f32x4 s = *(const f32x4*)(P + (size_t)i * 4);
#pragma unroll
  for (int z = 1; z < KS; ++z)
    s += *(const f32x4*)(P + (size_t)z * MN + i * 4);
  int n = (i * 4) % N;
#pragma unroll
  for (int u = 0; u < 4; ++u)
    store_o(C, (size_t)i * 4 + u, fmaxf(s[u] + bias[n + u], 0.f));
}

// ---------------------------------------------------------------------------
// K6: heads. One block per row, one wave per output (5 cls + 5 bbox).
// Output fp32, concat [class_logits(800x5); obb_preds(800x5)].
// ---------------------------------------------------------------------------
__global__ __launch_bounds__(640) void k_heads(const float* __restrict__ x2,
    const float* __restrict__ cls_w, const float* __restrict__ cls_b,
    const float* __restrict__ bbox_w, const float* __restrict__ bbox_b,
    float* __restrict__ out) {
  int n = blockIdx.x;
  int wave = threadIdx.x >> 6;   // 0..9
  int lane = threadIdx.x & 63;
  const float* w = (wave < 5) ? (cls_w + (size_t)wave * 1024)
                              : (bbox_w + (size_t)(wave - 5) * 1024);
  const float* xr = x2 + (size_t)n * 1024;
  float s = 0.f;
  for (int k = lane; k < 1024; k += 64) s += xr[k] * w[k];
  for (int off = 32; off; off >>= 1) s += __shfl_down(s, off, 64);
  if (lane == 0) {
    int o = (wave < 5) ? wave : wave - 5;
    float bias = (wave < 5) ? cls_b[o] : bbox_b[o];
    int base = (wave < 5) ? 0 : 4000;
    out[base + n * 5 + o] = s + bias;
  }
}

// ---------------------------------------------------------------------------
extern "C" void kernel_launch(void* const* d_in, const int* in_sizes, int n_in,
                              void* d_out, int out_size, void* d_ws, size_t ws_size,
                              hipStream_t stream) {
  const float* images     = (const float*)d_in[0];
  const float* backbone_w = (const float*)d_in[1];
  const float* backbone_b = (const float*)d_in[2];
  const float* rpn_w      = (const float*)d_in[3];
  const float* rpn_b      = (const float*)d_in[4];
  // d_in[5]/d_in[6] (obj_w/obj_b): conv output unused by the reference.
  const float* delta_w    = (const float*)d_in[7];
  const float* delta_b    = (const float*)d_in[8];
  const float* fc1_w      = (const float*)d_in[9];
  const float* fc1_b      = (const float*)d_in[10];
  const float* fc2_w      = (const float*)d_in[11];
  const float* fc2_b      = (const float*)d_in[12];
  const float* cls_w      = (const float*)d_in[13];
  const float* cls_b      = (const float*)d_in[14];
  const float* bbox_w     = (const float*)d_in[15];
  const float* bbox_b     = (const float*)d_in[16];

  char* ws = (char*)d_ws;
  float* f      = (float*)ws;                  //  8,388,608 B : f NHWC fp32
  float* boxes  = (float*)(ws + 8388608);      //     16,384 B (padded)
  bf16*  pooled = (bf16*) (ws + 8404992);      // 20,070,400 B : 800x12544 bf16
  bf16*  x1     = (bf16*) (ws + 28475392);     //  1,638,400 B : 800x1024 bf16
  float* x2     = (float*)(ws + 30113792);     //  3,276,800 B : 800x1024 fp32
  float* parts  = (float*)(ws + 33390592);     // 19,660,800 B : 6x800x1024 fp32
                                               // total 53.05 MB (<55.1 proven)
  // rpn partials reuse `parts` (16*32*256*4 = 512 KB; consumed by k_delta
  // before the FC1 GEMM overwrites the region — stream-ordered).
  float* rpart = parts;

  k_backbone<<<8192, 256, 0, stream>>>(images, backbone_w, backbone_b, f);
  k_rpn<<<dim3(32, 16), 256, 0, stream>>>(f, rpn_w, rpart);
  k_delta<<<32, 512, 0, stream>>>(rpart, rpn_b, delta_w, delta_b, boxes);
  k_roialign<<<800, 256, 0, stream>>>(f, boxes, pooled);

  // FC1: K=12544, split 6 (KC=2112: 5x33+31 iters of 64)
  k_gemm_sk<<<dim3(16, 13, 6), 256, 0, stream>>>(
      (const unsigned short*)pooled, fc1_w, parts, 800, 1024, 12544, 2112);
  k_reduce<bf16, 6><<<800, 256, 0, stream>>>(parts, fc1_b, x1, 819200, 1024);

  // FC2: K=1024, split 4 (KC=256)
  k_gemm_sk<<<dim3(16, 13, 4), 256, 0, stream>>>(
      (const unsigned short*)x1, fc2_w, parts, 800, 1024, 1024, 256);
  k_reduce<float, 4><<<800, 256, 0, stream>>>(parts, fc2_b, x2, 819200, 1024);

  k_heads<<<800, 640, 0, stream>>>(x2, cls_w, cls_b, bbox_w, bbox_b, (float*)d_out);
}

// Round 2
// 336.358 us; speedup vs baseline: 1.2659x; 1.0522x over previous
//
#include <hip/hip_runtime.h>
#include <hip/hip_bf16.h>

using bf16 = __hip_bfloat16;

typedef __attribute__((ext_vector_type(8))) short bf16x8;
typedef __attribute__((ext_vector_type(4))) float f32x4;

// async global->LDS, 16 B per lane, wave-uniform LDS base (+lane*16 by HW).
__device__ __forceinline__ void async16(const void* g, void* l) {
  __builtin_amdgcn_global_load_lds(
      (const __attribute__((address_space(1))) unsigned int*)g,
      (__attribute__((address_space(3))) unsigned int*)l, 16, 0, 0);
}

__device__ __forceinline__ void store_o(float* C, size_t i, float v) { C[i] = v; }
__device__ __forceinline__ void store_o(bf16* C, size_t i, float v) {
  C[i] = __float2bfloat16(v);
}

// ---------------------------------------------------------------------------
// K1: backbone conv (3->256, 3x3, stride16, pad1) fused with 2x2 avgpool.
// Output f NHWC fp32 (8,32,32,256). One block per (b,y,x), thread=cout.
// ---------------------------------------------------------------------------
__global__ __launch_bounds__(256) void k_backbone(const float* __restrict__ img,
    const float* __restrict__ w, const float* __restrict__ bias,
    float* __restrict__ f) {
  int blk = blockIdx.x;
  int x = blk & 31, y = (blk >> 5) & 31, b = blk >> 10;
  __shared__ float patch[4 * 27];   // [sub][cin*9+ky*3+kx]
  int t = threadIdx.x;
  if (t < 108) {
    int kx = t % 3, ky = (t / 3) % 3, cin = (t / 9) % 3, sub = t / 27;
    int sy = sub >> 1, sx = sub & 1;
    int iy = (2 * y + sy) * 16 - 1 + ky;   // max 1009 < 1024
    int ix = (2 * x + sx) * 16 - 1 + kx;
    float v = 0.f;
    if (iy >= 0 && ix >= 0)
      v = img[((size_t)(b * 3 + cin) * 1024 + iy) * 1024 + ix];
    patch[t] = v;
  }
  __syncthreads();
  int c = t;
  float wr[27];
#pragma unroll
  for (int k = 0; k < 27; ++k) wr[k] = w[c * 27 + k];
  float acc = 0.f;
#pragma unroll
  for (int sub = 0; sub < 4; ++sub)
#pragma unroll
    for (int k = 0; k < 27; ++k)
      acc += patch[sub * 27 + k] * wr[k];
  f[(size_t)blk * 256 + c] = acc * 0.25f + bias[c];
}

// ---------------------------------------------------------------------------
// K2a: RPN conv partials. grid (pos=32, kc=16), thread = cout.
// ---------------------------------------------------------------------------
__global__ __launch_bounds__(256) void k_rpn(const float* __restrict__ f,
    const float* __restrict__ rpn_w, float* __restrict__ part) {
  int p = blockIdx.x;        // 0..31 : b*4 + x
  int kc = blockIdx.y;       // 0..15 : 16-cin chunk
  int x = p & 3, b = p >> 2;
  __shared__ float fpl[6][16];   // [row*3+col][cin2]
  int tid = threadIdx.x;
  if (tid < 96) {
    int cin2 = tid & 15;
    int rc = tid >> 4;       // 0..5 = row*3+col
    int row = rc / 3, col = rc % 3;
    int xc = x - 1 + col;    // <= 5, always < 32
    float v = 0.f;
    if (xc >= 0)
      v = f[((size_t)(b * 32 + row) * 32 + xc) * 256 + kc * 16 + cin2];
    fpl[rc][cin2] = v;
  }
  __syncthreads();
  int c = tid;
  const float* wbase = rpn_w + (size_t)c * 2304 + kc * 144;
  float acc = 0.f;
#pragma unroll
  for (int cin2 = 0; cin2 < 16; ++cin2) {
    const float* wp = wbase + cin2 * 9;
    acc += fpl[0][cin2] * wp[3] + fpl[1][cin2] * wp[4]
         + fpl[2][cin2] * wp[5] + fpl[3][cin2] * wp[6]
         + fpl[4][cin2] * wp[7] + fpl[5][cin2] * wp[8];
  }
  part[((size_t)kc * 32 + p) * 256 + c] = acc;
}

// ---------------------------------------------------------------------------
// K2b: reduce partials + ReLU, delta conv (2 threads per output), decode.
// ---------------------------------------------------------------------------
__global__ __launch_bounds__(512) void k_delta(const float* __restrict__ part,
    const float* __restrict__ rpn_b,
    const float* __restrict__ dw, const float* __restrict__ db,
    float* __restrict__ boxes) {
  int p = blockIdx.x;        // 0..31
  int x = p & 3, b = p >> 2;
  __shared__ float tbuf[256];
  __shared__ float dvals[135];
  int tid = threadIdx.x;
  if (tid < 256) {
    float s = rpn_b[tid];
#pragma unroll
    for (int kc = 0; kc < 16; ++kc)
      s += part[((size_t)kc * 32 + p) * 256 + tid];
    tbuf[tid] = fmaxf(s, 0.f);
  }
  __syncthreads();
  if (tid < 270) {
    int o = tid >> 1, half = tid & 1;
    const float* wp = dw + (size_t)o * 256 + half * 128;
    const float* tp = tbuf + half * 128;
    float s = 0.f;
#pragma unroll 8
    for (int k = 0; k < 128; ++k) s += tp[k] * wp[k];
    s += __shfl_xor(s, 1, 64);   // pair (2o, 2o+1) always within one wave
    if (half == 0) dvals[o] = s + db[o];
  }
  __syncthreads();
  if (tid < 27) {
    int i = x * 27 + tid;
    if (i < 100) {
      int a = tid;
      int si = a / 9, ri = (a / 3) % 3, ai = a % 3;
      float scale = 32.f * (float)(1 << si);
      float sr = (ri == 0) ? 0.70710678118654752f : (ri == 1 ? 1.0f : 1.41421356237309505f);
      float aw = scale * sr, ah = scale / sr;
      float aang = 45.f * (float)ai;
      float acx = 32.f * (float)x, acy = 0.f;
      float* bx = boxes + (size_t)(b * 100 + i) * 5;
      bx[0] = dvals[a * 5 + 0] * aw + acx;
      bx[1] = dvals[a * 5 + 1] * ah + acy;
      bx[2] = expf(dvals[a * 5 + 2]) * aw;
      bx[3] = expf(dvals[a * 5 + 3]) * ah;
      bx[4] = aang + dvals[a * 5 + 4];
    }
  }
}

// ---------------------------------------------------------------------------
// K3: rotated ROI align. 800 blocks, thread=channel; writes pooled as bf16
// in (n, c*49+bin) order — the A operand of the FC1 MFMA GEMM.
// ---------------------------------------------------------------------------
__global__ __launch_bounds__(256) void k_roialign(const float* __restrict__ f,
    const float* __restrict__ boxes, bf16* __restrict__ pooled) {
  int n = blockIdx.x;
  int b = n / 100;
  __shared__ int six[49], siy[49];
  __shared__ float swx[49], swy[49];
  __shared__ float pool_s[12544];
  int tid = threadIdx.x;
  if (tid < 49) {
    float cx = boxes[n * 5 + 0], cy = boxes[n * 5 + 1];
    float w = boxes[n * 5 + 2], h = boxes[n * 5 + 3], ang = boxes[n * 5 + 4];
    float ar = -ang * 0.017453292519943295f;
    float cc = cosf(ar), ss = sinf(ar);
    float t00 = w * (1.f / 32.f) * cc, t01 = -h * (1.f / 32.f) * ss;
    float t02 = cx * (2.f / 32.f) - 1.f;
    float t10 = w * (1.f / 32.f) * ss, t11 = h * (1.f / 32.f) * cc;
    float t12 = cy * (2.f / 32.f) - 1.f;
    int py = tid / 7, px = tid - py * 7;
    float lx = (2.f * px + 1.f) * (1.f / 7.f) - 1.f;
    float ly = (2.f * py + 1.f) * (1.f / 7.f) - 1.f;
    float gx = t00 * lx + t01 * ly + t02;
    float gy = t10 * lx + t11 * ly + t12;
    float ix = ((gx + 1.f) * 32.f - 1.f) * 0.5f;
    float iy = ((gy + 1.f) * 32.f - 1.f) * 0.5f;
    float x0 = floorf(ix), y0 = floorf(iy);
    six[tid] = (int)x0; siy[tid] = (int)y0;
    swx[tid] = ix - x0; swy[tid] = iy - y0;
  }
  __syncthreads();
  const float* fb = f + (size_t)b * 262144;
  int c = tid;
  for (int bin = 0; bin < 49; ++bin) {
    int x0 = six[bin], y0 = siy[bin];
    float wx = swx[bin], wy = swy[bin];
    float acc = 0.f;
    if (x0 >= 0 && x0 < 32 && y0 >= 0 && y0 < 32)
      acc += fb[(y0 * 32 + x0) * 256 + c] * ((1.f - wx) * (1.f - wy));
    if (x0 + 1 >= 0 && x0 + 1 < 32 && y0 >= 0 && y0 < 32)
      acc += fb[(y0 * 32 + x0 + 1) * 256 + c] * (wx * (1.f - wy));
    if (x0 >= 0 && x0 < 32 && y0 + 1 >= 0 && y0 + 1 < 32)
      acc += fb[((y0 + 1) * 32 + x0) * 256 + c] * ((1.f - wx) * wy);
    if (x0 + 1 >= 0 && x0 + 1 < 32 && y0 + 1 >= 0 && y0 + 1 < 32)
      acc += fb[((y0 + 1) * 32 + x0 + 1) * 256 + c] * (wx * wy);
    pool_s[c * 49 + bin] = acc;
  }
  __syncthreads();
  bf16* po = pooled + (size_t)n * 12544;
  for (int k = tid; k < 12544; k += 256) po[k] = __float2bfloat16(pool_s[k]);
}

// ---------------------------------------------------------------------------
// K4: split-K MFMA GEMM partial: P[z] = A[:, kbeg:kend] * B[:, kbeg:kend]^T.
// Tile 128(M)x64(N), BK=64, 4 waves in a 2x2 grid (each wave: 64x32 out,
// 4x2 fragments, 16 MFMA/K-step — 2x the density of the old 64x64 tile).
// A: MxK bf16 (async LDS, XOR-seg swizzle), B: NxK fp32 (inline cvt,
// rows padded to 72 shorts). grid (N/64, ceil(M/128), KS).
// ---------------------------------------------------------------------------
__global__ __launch_bounds__(256) void k_gemm_sk(
    const unsigned short* __restrict__ A, const float* __restrict__ B,
    float* __restrict__ P, int M, int N, int K, int KC) {
  __shared__ unsigned short As[128 * 64];  // 16 KB, XOR-swizzled segs
  __shared__ unsigned short Bs[64 * 72];   // 9 KB, padded rows
  int t = threadIdx.x;
  int wv = t >> 6, ln = t & 63;
  int quad = ln >> 4, l15 = ln & 15;
  int wm = wv >> 1, wn = wv & 1;           // 2x2 wave grid
  int n0 = blockIdx.x * 64, m0 = blockIdx.y * 128;
  int kbeg = blockIdx.z * KC;
  int kend = kbeg + KC; if (kend > K) kend = K;

  // A staging: 4 calls/wave; call q covers within-tile rows q*32+wv*8+(ln>>3).
  // Within-tile row & 7 == ln>>3 for every q, so the XOR swizzle slot is the
  // same as the 64-row version: LDS slot (ln&7) holds global seg (ln&7)^(ln>>3).
  int srow = ln >> 3;                      // 0..7
  int sg = (ln & 7) ^ srow;
  const unsigned short* Ap[4];
#pragma unroll
  for (int q = 0; q < 4; ++q) {
    int r = m0 + q * 32 + wv * 8 + srow;
    if (r > M - 1) r = M - 1;
    Ap[q] = A + (size_t)r * K + sg * 8;
  }

  // B staging: thread covers row t>>2, 16 floats at (t&3)*16.
  int brow = t >> 2, bq = t & 3;
  const float* Bp = B + (size_t)(n0 + brow) * K + bq * 16;
  unsigned short* bdst = &Bs[brow * 72 + bq * 16];

  f32x4 acc[4][2];
#pragma unroll
  for (int mf = 0; mf < 4; ++mf)
#pragma unroll
    for (int nf = 0; nf < 2; ++nf) acc[mf][nf] = (f32x4){0.f, 0.f, 0.f, 0.f};

  for (int k0 = kbeg; k0 < kend; k0 += 64) {
    float4 bv0 = *(const float4*)(Bp + k0);
    float4 bv1 = *(const float4*)(Bp + k0 + 4);
    float4 bv2 = *(const float4*)(Bp + k0 + 8);
    float4 bv3 = *(const float4*)(Bp + k0 + 12);
    __syncthreads();   // previous iteration's compute done
#pragma unroll
    for (int q = 0; q < 4; ++q)
      async16(Ap[q] + k0, &As[q * 2048 + wv * 512]);
    unsigned short bb[16];
    bb[0]  = __bfloat16_as_ushort(__float2bfloat16(bv0.x));
    bb[1]  = __bfloat16_as_ushort(__float2bfloat16(bv0.y));
    bb[2]  = __bfloat16_as_ushort(__float2bfloat16(bv0.z));
    bb[3]  = __bfloat16_as_ushort(__float2bfloat16(bv0.w));
    bb[4]  = __bfloat16_as_ushort(__float2bfloat16(bv1.x));
    bb[5]  = __bfloat16_as_ushort(__float2bfloat16(bv1.y));
    bb[6]  = __bfloat16_as_ushort(__float2bfloat16(bv1.z));
    bb[7]  = __bfloat16_as_ushort(__float2bfloat16(bv1.w));
    bb[8]  = __bfloat16_as_ushort(__float2bfloat16(bv2.x));
    bb[9]  = __bfloat16_as_ushort(__float2bfloat16(bv2.y));
    bb[10] = __bfloat16_as_ushort(__float2bfloat16(bv2.z));
    bb[11] = __bfloat16_as_ushort(__float2bfloat16(bv2.w));
    bb[12] = __bfloat16_as_ushort(__float2bfloat16(bv3.x));
    bb[13] = __bfloat16_as_ushort(__float2bfloat16(bv3.y));
    bb[14] = __bfloat16_as_ushort(__float2bfloat16(bv3.z));
    bb[15] = __bfloat16_as_ushort(__float2bfloat16(bv3.w));
#pragma unroll
    for (int u = 0; u < 2; ++u)
      *(bf16x8*)(bdst + u * 8) = *(const bf16x8*)(bb + u * 8);
    __syncthreads();   // drains vmcnt (async A) + lgkm (B writes)
#pragma unroll
    for (int ks = 0; ks < 2; ++ks) {
      bf16x8 a[4];
#pragma unroll
      for (int mf = 0; mf < 4; ++mf) {
        int row = wm * 64 + mf * 16 + l15;           // row & 7 == l15 & 7
        a[mf] = *(const bf16x8*)&As[row * 64 + (((ks * 4 + quad) ^ (l15 & 7)) * 8)];
      }
#pragma unroll
      for (int nf = 0; nf < 2; ++nf) {
        bf16x8 b = *(const bf16x8*)&Bs[(wn * 32 + nf * 16 + l15) * 72 + ks * 32 + quad * 8];
#pragma unroll
        for (int mf = 0; mf < 4; ++mf)
          acc[mf][nf] = __builtin_amdgcn_mfma_f32_16x16x32_bf16(a[mf], b, acc[mf][nf], 0, 0, 0);
      }
    }
  }
  // store fp32 partials; D layout m = quad*4+r, n = l15 (within 16x16).
  float* Pz = P + (size_t)blockIdx.z * M * N;
#pragma unroll
  for (int nf = 0; nf < 2; ++nf) {
    int n = n0 + wn * 32 + nf * 16 + l15;
#pragma unroll
    for (int mf = 0; mf < 4; ++mf) {
#pragma unroll
      for (int r = 0; r < 4; ++r) {
        int m = m0 + wm * 64 + mf * 16 + quad * 4 + r;
        if (m < M) Pz[(size_t)m * N + n] = acc[mf][nf][r];
      }
    }
  }
}

// ---------------------------------------------------------------------------
// K5: split-K reduce: C = relu(sum_z P[z] + bias). float4-vectorized.
// ---------------------------------------------------------------------------
template <typename OutT, int KS>
__global__ __launch_bounds__(256) void k_reduce(const float* __restrict__ P,
    const float* __restrict__ bias, OutT* __restrict__ C, int MN, int N) {
  int i = blockIdx.x * 256 + threadIdx.x;   // float4 index
  if (i * 4 >= MN) return;
  f32x4 s = *(const f32x4*)(P + (size_t)i * 4);
#pragma unroll
  for (int z = 1; z < KS; ++z)
    s += *(const f32x4*)(P + (size_t)z * MN + i * 4);
  int n = (i * 4) % N;
#pragma unroll
  for (int u = 0; u < 4; ++u)
    store_o(C, (size_t)i * 4 + u, fmaxf(s[u] + bias[n + u], 0.f));
}

// ---------------------------------------------------------------------------
// K6: heads. One block per row, one wave per output (5 cls + 5 bbox).
// ---------------------------------------------------------------------------
__global__ __launch_bounds__(640) void k_heads(const float* __restrict__ x2,
    const float* __restrict__ cls_w, const float* __restrict__ cls_b,
    const float* __restrict__ bbox_w, const float* __restrict__ bbox_b,
    float* __restrict__ out) {
  int n = blockIdx.x;
  int wave = threadIdx.x >> 6;   // 0..9
  int lane = threadIdx.x & 63;
  const float* w = (wave < 5) ? (cls_w + (size_t)wave * 1024)
                              : (bbox_w + (size_t)(wave - 5) * 1024);
  const float* xr = x2 + (size_t)n * 1024;
  float s = 0.f;
  for (int k = lane; k < 1024; k += 64) s += xr[k] * w[k];
  for (int off = 32; off; off >>= 1) s += __shfl_down(s, off, 64);
  if (lane == 0) {
    int o = (wave < 5) ? wave : wave - 5;
    float bias = (wave < 5) ? cls_b[o] : bbox_b[o];
    int base = (wave < 5) ? 0 : 4000;
    out[base + n * 5 + o] = s + bias;
  }
}

// ---------------------------------------------------------------------------
extern "C" void kernel_launch(void* const* d_in, const int* in_sizes, int n_in,
                              void* d_out, int out_size, void* d_ws, size_t ws_size,
                              hipStream_t stream) {
  const float* images     = (const float*)d_in[0];
  const float* backbone_w = (const float*)d_in[1];
  const float* backbone_b = (const float*)d_in[2];
  const float* rpn_w      = (const float*)d_in[3];
  const float* rpn_b      = (const float*)d_in[4];
  // d_in[5]/d_in[6] (obj_w/obj_b): conv output unused by the reference.
  const float* delta_w    = (const float*)d_in[7];
  const float* delta_b    = (const float*)d_in[8];
  const float* fc1_w      = (const float*)d_in[9];
  const float* fc1_b      = (const float*)d_in[10];
  const float* fc2_w      = (const float*)d_in[11];
  const float* fc2_b      = (const float*)d_in[12];
  const float* cls_w      = (const float*)d_in[13];
  const float* cls_b      = (const float*)d_in[14];
  const float* bbox_w     = (const float*)d_in[15];
  const float* bbox_b     = (const float*)d_in[16];

  char* ws = (char*)d_ws;
  float* f      = (float*)ws;                  //  8,388,608 B : f NHWC fp32
  float* boxes  = (float*)(ws + 8388608);      //     16,384 B (padded)
  bf16*  pooled = (bf16*) (ws + 8404992);      // 20,070,400 B : 800x12544 bf16
  bf16*  x1     = (bf16*) (ws + 28475392);     //  1,638,400 B : 800x1024 bf16
  float* x2     = (float*)(ws + 30113792);     //  3,276,800 B : 800x1024 fp32
  float* parts  = (float*)(ws + 33390592);     // 19,660,800 B : 6x800x1024 fp32
                                               // total 53.05 MB (<55.1 proven)
  // rpn partials reuse `parts` (16*32*256*4 = 512 KB; consumed by k_delta
  // before the FC1 GEMM overwrites the region — stream-ordered).
  float* rpart = parts;

  k_backbone<<<8192, 256, 0, stream>>>(images, backbone_w, backbone_b, f);
  k_rpn<<<dim3(32, 16), 256, 0, stream>>>(f, rpn_w, rpart);
  k_delta<<<32, 512, 0, stream>>>(rpart, rpn_b, delta_w, delta_b, boxes);
  k_roialign<<<800, 256, 0, stream>>>(f, boxes, pooled);

  // FC1: K=12544, split 6 (KC=2112: 5x33+31 iters of 64). grid 16x7x6=672.
  k_gemm_sk<<<dim3(16, 7, 6), 256, 0, stream>>>(
      (const unsigned short*)pooled, fc1_w, parts, 800, 1024, 12544, 2112);
  k_reduce<bf16, 6><<<800, 256, 0, stream>>>(parts, fc1_b, x1, 819200, 1024);

  // FC2: K=1024, split 4 (KC=256). grid 16x7x4=448.
  k_gemm_sk<<<dim3(16, 7, 4), 256, 0, stream>>>(
      (const unsigned short*)x1, fc2_w, parts, 800, 1024, 1024, 256);
  k_reduce<float, 4><<<800, 256, 0, stream>>>(parts, fc2_b, x2, 819200, 1024);

  k_heads<<<800, 640, 0, stream>>>(x2, cls_w, cls_b, bbox_w, bbox_b, (float*)d_out);
}